// Round 11
// baseline (322.600 us; speedup 1.0000x reference)
//
#include <hip/hip_runtime.h>
#include <hip/hip_bf16.h>
#include <math.h>

// MoE: B=2,S=1024,D=1024,E=8,H=3584, top-1 routing.
// router(+x->bf16) -> aux -> scatter
//  -> ggemm<GATHER>: g1=x@W1^T, g2=x@W2^T   (z = expert x matrix)
//  -> swiglu (g1 <- silu(g1)*g2)
//  -> ggemm<ATOMIC>: out += h@W3^T (split-K=2, 2 atomic adds/address)
// GEMM core (r11): BM=384 covers the whole expert -> weights read ONCE.
// BK=32, BN=64, 512 thr / 8 waves (4M x 2N), LDS 58.9KB -> 2 blocks/CU.
// A: kb-major [buf][kb][row][16B] dbuf'd global_load_lds (L2-resident bf16).
// B: 1 f32x4/thread, 2 named reg sets (2-iter age) -> bf16 LDS dbuf.
// Steady barrier = CBAR(1): retire previous A-DMA only; newest B-load stays
// in flight across EVERY barrier. writeB's compiler vmcnt(4) = 1-iter cover.

#define NS 1024
#define ND 1024
#define NE 8
#define NH 3584
#define NTOK 2048

typedef float f32x4 __attribute__((ext_vector_type(4)));
typedef __bf16 bf16x8 __attribute__((ext_vector_type(8)));
typedef unsigned short u16x4 __attribute__((ext_vector_type(4)));
typedef unsigned short u16x8 __attribute__((ext_vector_type(8)));

#define LBAR()  asm volatile("s_waitcnt lgkmcnt(0)\n\ts_barrier" ::: "memory")
#define CBAR(N) asm volatile("s_waitcnt vmcnt(" #N ") lgkmcnt(0)\n\ts_barrier" ::: "memory")

__device__ __forceinline__ unsigned short f2b(float f) {
  return __builtin_bit_cast(unsigned short, (__bf16)f);
}
__device__ __forceinline__ u16x4 cvt4(f32x4 v) {
  u16x4 r;
  r[0] = f2b(v[0]); r[1] = f2b(v[1]); r[2] = f2b(v[2]); r[3] = f2b(v[3]);
  return r;
}
__device__ __forceinline__ void gl_lds16(const void* g, void* l) {
  __builtin_amdgcn_global_load_lds(
      (const __attribute__((address_space(1))) unsigned int*)g,
      (__attribute__((address_space(3))) unsigned int*)l, 16, 0, 0);
}

// ---------------- router (+ x f32 -> bf16) ----------------
__global__ __launch_bounds__(256) void router_kernel(
    const float* __restrict__ x, const float* __restrict__ Wr,
    float* __restrict__ probs, float* __restrict__ lse,
    int* __restrict__ counts, int* __restrict__ expert_of,
    unsigned short* __restrict__ xb)
{
  int n = blockIdx.x;
  int t = threadIdx.x;
  const float* xr = x + (size_t)n * ND;
  float xv[4];
#pragma unroll
  for (int j = 0; j < 4; ++j) xv[j] = xr[t + j * 256];
#pragma unroll
  for (int j = 0; j < 4; ++j)
    xb[(size_t)n * ND + t + j * 256] = f2b(xv[j]);
  float p[NE];
#pragma unroll
  for (int e = 0; e < NE; ++e) p[e] = 0.f;
#pragma unroll
  for (int j = 0; j < 4; ++j) {
    int d = t + j * 256;
#pragma unroll
    for (int e = 0; e < NE; ++e) p[e] += xv[j] * Wr[e * ND + d];
  }
#pragma unroll
  for (int e = 0; e < NE; ++e) {
#pragma unroll
    for (int o = 32; o > 0; o >>= 1) p[e] += __shfl_down(p[e], o, 64);
  }
  __shared__ float red[4][NE];
  int wid = t >> 6, lane = t & 63;
  if (lane == 0) {
#pragma unroll
    for (int e = 0; e < NE; ++e) red[wid][e] = p[e];
  }
  __syncthreads();
  if (t == 0) {
    float lg[NE];
#pragma unroll
    for (int e = 0; e < NE; ++e) lg[e] = red[0][e] + red[1][e] + red[2][e] + red[3][e];
    float m = lg[0]; int arg = 0;
#pragma unroll
    for (int e = 1; e < NE; ++e) if (lg[e] > m) { m = lg[e]; arg = e; }
    float s = 0.f, ex[NE];
#pragma unroll
    for (int e = 0; e < NE; ++e) { ex[e] = expf(lg[e] - m); s += ex[e]; }
    float inv = 1.f / s;
#pragma unroll
    for (int e = 0; e < NE; ++e) probs[n * NE + e] = ex[e] * inv;
    lse[n] = m + logf(s);
    expert_of[n] = arg;
    atomicAdd(&counts[arg], 1);
  }
}

// ---------------- aux losses + offsets ----------------
__global__ __launch_bounds__(256) void aux_offsets_kernel(
    const float* __restrict__ probs, const float* __restrict__ lse,
    const int* __restrict__ counts, int* __restrict__ offsets,
    int* __restrict__ cursors, float* __restrict__ out_aux)
{
  int t = threadIdx.x;
  float lsum = 0.f;
  for (int n = t; n < NTOK; n += 256) lsum += lse[n];
  float esum = 0.f, esq = 0.f;
  for (int i = t; i < NS * NE; i += 256) {
    float v = probs[i] + probs[NS * NE + i];
    esum += v; esq += v * v;
  }
  __shared__ float rb[3][4];
  int wid = t >> 6, lane = t & 63;
#pragma unroll
  for (int o = 32; o > 0; o >>= 1) {
    lsum += __shfl_down(lsum, o, 64);
    esum += __shfl_down(esum, o, 64);
    esq  += __shfl_down(esq, o, 64);
  }
  if (lane == 0) { rb[0][wid] = lsum; rb[1][wid] = esum; rb[2][wid] = esq; }
  __syncthreads();
  if (t == 0) {
    lsum = rb[0][0] + rb[0][1] + rb[0][2] + rb[0][3];
    esum = rb[1][0] + rb[1][1] + rb[1][2] + rb[1][3];
    esq  = rb[2][0] + rb[2][1] + rb[2][2] + rb[2][3];
    float zmean = lsum / (float)NTOK;
    float z_loss = zmean * zmean;
    const float nn = (float)(NS * NE);
    float mean = esum / nn;
    float var = (esq - esum * esum / nn) / (nn - 1.0f);
    float load_loss = var / (mean * mean);
    out_aux[0] = 1e-3f * z_loss + 1e-3f * load_loss;
    int off = 0;
#pragma unroll
    for (int e = 0; e < NE; ++e) { offsets[e] = off; cursors[e] = off; off += counts[e]; }
    offsets[NE] = off;
  }
}

// ---------------- token lists ----------------
__global__ __launch_bounds__(256) void scatter_kernel(
    const int* __restrict__ expert_of, int* __restrict__ cursors,
    int* __restrict__ token_list)
{
  int n = blockIdx.x * 256 + threadIdx.x;
  int e = expert_of[n];
  int p = atomicAdd(&cursors[e], 1);
  token_list[p] = n;
}

// ---------------- grouped GEMM: weights once, drain-free, 2 blk/CU --------
template<int NSTEP, int LDA, int LDW, bool GATHER, bool ATOMIC>
__global__ __launch_bounds__(512, 4) void ggemm(
    const unsigned short* __restrict__ Ab,
    const float* __restrict__ Wa, const float* __restrict__ Wb,
    const int* __restrict__ offsets, const int* __restrict__ token_list,
    unsigned short* __restrict__ ga, unsigned short* __restrict__ gb,
    float* __restrict__ outp)
{
  const int e = blockIdx.z & 7;
  const int sel = blockIdx.z >> 3;          // matrix (GATHER) | k-half
  const int base = offsets[e], cnt = offsets[e + 1] - base;
  if (cnt <= 0) return;
  const int n0 = blockIdx.x * 64;
  int akoff;
  const float* W;
  unsigned short* g = nullptr;
  if constexpr (GATHER) {
    akoff = 0;
    W = (sel ? Wb : Wa) + (size_t)e * ((size_t)NH * ND) + (size_t)n0 * LDW;
    g = sel ? gb : ga;
  } else {
    akoff = sel * (NSTEP * 32);
    W = Wa + (size_t)e * ((size_t)NH * ND) + (size_t)n0 * LDW + akoff;
  }

  __shared__ __align__(16) unsigned short As[2][4][384][8];  // 48 KB  [buf][kb][row][16B]
  __shared__ __align__(16) unsigned short Bs[2][4][64][8];   //  8 KB  [buf][kb][nrow][16B]
  __shared__ int rtk[384];

  const int t = threadIdx.x, l = t & 63, w = t >> 6;
  const int rl = l & 15, rq = l >> 4;
  const int wm = (w >> 1) * 96, wn = (w & 1) * 32;

  // B staging map: thread -> (nrow, 4 f32 k-cols); one f32x4 per thread/iter
  const int bNrow = t >> 3, bKc = t & 7;
  const float* bp = W + (size_t)bNrow * LDW + bKc * 4;
  char* bdst = (char*)&Bs[0][0][0][0] + (bKc >> 1) * 1024 + bNrow * 16 + (bKc & 1) * 8;

  const int kbA = w >> 1;            // this wave's A k-block (0..3)
  const int arb = (w & 1) * 192;     // row base

  for (int c0 = 0; c0 < cnt; c0 += 384) {
    __syncthreads();
    for (int r = t; r < 384; r += 512) {
      int mc = c0 + r; if (mc > cnt - 1) mc = cnt - 1;
      rtk[r] = token_list[base + mc];
    }
    __syncthreads();

    const unsigned short* aSrc[3];
#pragma unroll
    for (int i = 0; i < 3; ++i) {
      int rr = arb + i * 64 + l;
      size_t row;
      if constexpr (GATHER) {
        row = (size_t)rtk[rr];
      } else {
        int mc = c0 + rr; if (mc > cnt - 1) mc = cnt - 1;
        row = (size_t)(base + mc);
      }
      aSrc[i] = Ab + row * LDA + akoff + kbA * 8;
    }
    auto stageA = [&](int buf, int k) {
      char* d = (char*)&As[0][0][0][0] + buf * 24576 + kbA * 6144 + arb * 16;
#pragma unroll
      for (int i = 0; i < 3; ++i)
        gl_lds16(aSrc[i] + (size_t)k * 32, d + i * 1024);
    };

    f32x4 s0, s1;
    auto writeB = [&](int buf, const f32x4& v) {
      *(u16x4*)(bdst + buf * 4096) = cvt4(v);
    };

    f32x4 acc[6][2] = {};
    auto domfma = [&](int buf) {
      const char* Ba = (const char*)&Bs[0][0][0][0] + buf * 4096 + rq * 1024;
      const char* Aa = (const char*)&As[0][0][0][0] + buf * 24576 + rq * 6144;
      bf16x8 bf0 = *(const bf16x8*)(Ba + (wn + rl) * 16);
      bf16x8 bf1 = *(const bf16x8*)(Ba + (wn + 16 + rl) * 16);
#pragma unroll
      for (int i = 0; i < 6; ++i) {
        bf16x8 af = *(const bf16x8*)(Aa + (wm + i * 16 + rl) * 16);
        acc[i][0] = __builtin_amdgcn_mfma_f32_16x16x32_bf16(af, bf0, acc[i][0], 0, 0, 0);
        acc[i][1] = __builtin_amdgcn_mfma_f32_16x16x32_bf16(af, bf1, acc[i][1], 0, 0, 0);
      }
    };

    // prologue: A(0) DMA; B(0),B(1) loads; publish B(0)
    stageA(0, 0);
    s0 = *(const f32x4*)(bp);
    s1 = *(const f32x4*)(bp + 32);
    writeB(0, s0);        // auto vmcnt(1): retires A(0)+B(0), keeps B(1)
    LBAR();

    // main: pairs (k even -> buf0, k+1 -> buf1); all guards true
    int k = 0;
    for (; k + 3 < NSTEP; k += 2) {
      stageA(1, k + 1);                              // 3 DMA
      s0 = *(const f32x4*)(bp + (size_t)(k + 2) * 32);
      domfma(0);
      writeB(1, s1);       // auto vmcnt(4): retire B(k+1); keep A+newest B
      CBAR(1);             // retire A(k+1); keep B(k+2) in flight
      stageA(0, k + 2);
      s1 = *(const f32x4*)(bp + (size_t)(k + 3) * 32);
      domfma(1);
      writeB(0, s0);
      CBAR(1);             // retire A(k+2); keep B(k+3)
    }
    // tail: k = NSTEP-2 (buf0), NSTEP-1 (buf1)
    stageA(1, NSTEP - 1);
    domfma(0);
    writeB(1, s1);
    CBAR(0);
    domfma(1);

    // epilogue
#pragma unroll
    for (int i = 0; i < 6; ++i) {
#pragma unroll
      for (int r = 0; r < 4; ++r) {
        int mrow = wm + i * 16 + rq * 4 + r;
        int m = c0 + mrow;
        if (m < cnt) {
#pragma unroll
          for (int j = 0; j < 2; ++j) {
            int col = n0 + wn + j * 16 + rl;
            float v = acc[i][j][r];
            if constexpr (ATOMIC) {
              atomicAdd(&outp[(size_t)rtk[mrow] * ND + col], v);
            } else {
              g[(size_t)(base + m) * NH + col] = f2b(v);
            }
          }
        }
      }
    }
  }
}

// ---------------- SwiGLU in-place: g1 <- silu(g1)*g2 ----------------
__global__ __launch_bounds__(256) void swiglu_kernel(
    unsigned short* __restrict__ g1, const unsigned short* __restrict__ g2)
{
  size_t i = ((size_t)blockIdx.x * 256 + threadIdx.x) * 8;
  u16x8 a = *(const u16x8*)(g1 + i);
  u16x8 b = *(const u16x8*)(g2 + i);
  u16x8 o;
#pragma unroll
  for (int j = 0; j < 8; ++j) {
    float av = __builtin_bit_cast(float, (unsigned int)a[j] << 16);
    float bv = __builtin_bit_cast(float, (unsigned int)b[j] << 16);
    o[j] = f2b(av / (1.f + expf(-av)) * bv);
  }
  *(u16x8*)(g1 + i) = o;
}

extern "C" void kernel_launch(void* const* d_in, const int* in_sizes, int n_in,
                              void* d_out, int out_size, void* d_ws, size_t ws_size,
                              hipStream_t stream)
{
  (void)in_sizes; (void)n_in; (void)out_size; (void)ws_size;
  const float* x  = (const float*)d_in[0];
  const float* Wr = (const float*)d_in[1];
  const float* W1 = (const float*)d_in[2];
  const float* W2 = (const float*)d_in[3];
  const float* W3 = (const float*)d_in[4];
  float* out = (float*)d_out;

  char* w = (char*)d_ws;
  float* probs    = (float*)(w + 0);        // 65536 B
  float* lse      = (float*)(w + 65536);    // 8192 B
  int* counts     = (int*)(w + 73728);      // 32 B
  int* cursors    = (int*)(w + 73760);      // 32 B
  int* offsets    = (int*)(w + 73792);      // 64 B
  int* expert_of  = (int*)(w + 73856);      // 8192 B
  int* token_list = (int*)(w + 82048);      // 8192 B
  unsigned short* g1 = (unsigned short*)(w + 131072);            // 14680064 B (-> h)
  unsigned short* g2 = g1 + (size_t)NTOK * NH;                   // 14680064 B
  unsigned short* xb = (unsigned short*)((char*)g2 + (size_t)NTOK * NH * 2); // 4 MB

  hipMemsetAsync(counts, 0, 32, stream);
  hipMemsetAsync(out, 0, (size_t)NTOK * ND * sizeof(float), stream);
  router_kernel<<<NTOK, 256, 0, stream>>>(x, Wr, probs, lse, counts, expert_of, xb);
  aux_offsets_kernel<<<1, 256, 0, stream>>>(probs, lse, counts, offsets, cursors,
                                            out + (size_t)NTOK * ND);
  scatter_kernel<<<NTOK / 256, 256, 0, stream>>>(expert_of, cursors, token_list);
  // g1 = x@W1^T, g2 = x@W2^T : weights read once (z = expert(8) x matrix(2))
  ggemm<ND / 32, ND, ND, true, false><<<dim3(NH / 64, 1, 16), 512, 0, stream>>>(
      xb, W1, W2, offsets, token_list, g1, g2, nullptr);
  swiglu_kernel<<<(NTOK * NH) / (256 * 8), 256, 0, stream>>>(g1, g2);
  // out += h@W3^T : split-K=2 (z = expert(8) x khalf(2)), W3 read once
  ggemm<(NH / 2) / 32, NH, NH, false, true><<<dim3(ND / 64, 1, 16), 512, 0, stream>>>(
      g1, W3, nullptr, offsets, token_list, nullptr, nullptr, out);
}

// Round 12
// 240.607 us; speedup vs baseline: 1.3408x; 1.3408x over previous
//
#include <hip/hip_runtime.h>
#include <hip/hip_bf16.h>
#include <math.h>

// MoE: B=2,S=1024,D=1024,E=8,H=3584, top-1 routing.
// router(+x->bf16) -> aux -> scatter
//  -> ggemm<GATHER>: g1=x@W1^T, g2=x@W2^T (z = expert x matrix, weights ONCE)
//  -> swiglu (g1 <- silu(g1)*g2)
//  -> ggemm<ATOMIC>: out += h@W3^T (split-K=2, 2 atomic adds/address)
// r12 core: FIFO-clean step. BM=384 (whole expert), BN=32, BK=64, 512thr/8w.
// A: 48KB single-buf LDS; per step: ds_read ALL frags -> regs; lgkm+barrier;
// stageA(k+1) DMA; writeB(set loaded 2 steps ago); loadB(k+3); MFMA reg-only;
// CBAR(1) keeps ONLY the just-issued B-load. No wait ever touches a load
// younger than its latency at steady HBM pace. sched_barrier pins order.

#define NS 1024
#define ND 1024
#define NE 8
#define NH 3584
#define NTOK 2048

typedef float f32x4 __attribute__((ext_vector_type(4)));
typedef __bf16 bf16x8 __attribute__((ext_vector_type(8)));
typedef unsigned short u16x4 __attribute__((ext_vector_type(4)));
typedef unsigned short u16x8 __attribute__((ext_vector_type(8)));

#define LBAR()  asm volatile("s_waitcnt lgkmcnt(0)\n\ts_barrier" ::: "memory")
#define CBAR(N) asm volatile("s_waitcnt vmcnt(" #N ") lgkmcnt(0)\n\ts_barrier" ::: "memory")
#define SBAR()  __builtin_amdgcn_sched_barrier(0)

__device__ __forceinline__ unsigned short f2b(float f) {
  return __builtin_bit_cast(unsigned short, (__bf16)f);
}
__device__ __forceinline__ u16x4 cvt4(f32x4 v) {
  u16x4 r;
  r[0] = f2b(v[0]); r[1] = f2b(v[1]); r[2] = f2b(v[2]); r[3] = f2b(v[3]);
  return r;
}
__device__ __forceinline__ void gl_lds16(const void* g, void* l) {
  __builtin_amdgcn_global_load_lds(
      (const __attribute__((address_space(1))) unsigned int*)g,
      (__attribute__((address_space(3))) unsigned int*)l, 16, 0, 0);
}

// ---------------- router (+ x f32 -> bf16) ----------------
__global__ __launch_bounds__(256) void router_kernel(
    const float* __restrict__ x, const float* __restrict__ Wr,
    float* __restrict__ probs, float* __restrict__ lse,
    int* __restrict__ counts, int* __restrict__ expert_of,
    unsigned short* __restrict__ xb)
{
  int n = blockIdx.x;
  int t = threadIdx.x;
  const float* xr = x + (size_t)n * ND;
  float xv[4];
#pragma unroll
  for (int j = 0; j < 4; ++j) xv[j] = xr[t + j * 256];
#pragma unroll
  for (int j = 0; j < 4; ++j)
    xb[(size_t)n * ND + t + j * 256] = f2b(xv[j]);
  float p[NE];
#pragma unroll
  for (int e = 0; e < NE; ++e) p[e] = 0.f;
#pragma unroll
  for (int j = 0; j < 4; ++j) {
    int d = t + j * 256;
#pragma unroll
    for (int e = 0; e < NE; ++e) p[e] += xv[j] * Wr[e * ND + d];
  }
#pragma unroll
  for (int e = 0; e < NE; ++e) {
#pragma unroll
    for (int o = 32; o > 0; o >>= 1) p[e] += __shfl_down(p[e], o, 64);
  }
  __shared__ float red[4][NE];
  int wid = t >> 6, lane = t & 63;
  if (lane == 0) {
#pragma unroll
    for (int e = 0; e < NE; ++e) red[wid][e] = p[e];
  }
  __syncthreads();
  if (t == 0) {
    float lg[NE];
#pragma unroll
    for (int e = 0; e < NE; ++e) lg[e] = red[0][e] + red[1][e] + red[2][e] + red[3][e];
    float m = lg[0]; int arg = 0;
#pragma unroll
    for (int e = 1; e < NE; ++e) if (lg[e] > m) { m = lg[e]; arg = e; }
    float s = 0.f, ex[NE];
#pragma unroll
    for (int e = 0; e < NE; ++e) { ex[e] = expf(lg[e] - m); s += ex[e]; }
    float inv = 1.f / s;
#pragma unroll
    for (int e = 0; e < NE; ++e) probs[n * NE + e] = ex[e] * inv;
    lse[n] = m + logf(s);
    expert_of[n] = arg;
    atomicAdd(&counts[arg], 1);
  }
}

// ---------------- aux losses + offsets ----------------
__global__ __launch_bounds__(256) void aux_offsets_kernel(
    const float* __restrict__ probs, const float* __restrict__ lse,
    const int* __restrict__ counts, int* __restrict__ offsets,
    int* __restrict__ cursors, float* __restrict__ out_aux)
{
  int t = threadIdx.x;
  float lsum = 0.f;
  for (int n = t; n < NTOK; n += 256) lsum += lse[n];
  float esum = 0.f, esq = 0.f;
  for (int i = t; i < NS * NE; i += 256) {
    float v = probs[i] + probs[NS * NE + i];
    esum += v; esq += v * v;
  }
  __shared__ float rb[3][4];
  int wid = t >> 6, lane = t & 63;
#pragma unroll
  for (int o = 32; o > 0; o >>= 1) {
    lsum += __shfl_down(lsum, o, 64);
    esum += __shfl_down(esum, o, 64);
    esq  += __shfl_down(esq, o, 64);
  }
  if (lane == 0) { rb[0][wid] = lsum; rb[1][wid] = esum; rb[2][wid] = esq; }
  __syncthreads();
  if (t == 0) {
    lsum = rb[0][0] + rb[0][1] + rb[0][2] + rb[0][3];
    esum = rb[1][0] + rb[1][1] + rb[1][2] + rb[1][3];
    esq  = rb[2][0] + rb[2][1] + rb[2][2] + rb[2][3];
    float zmean = lsum / (float)NTOK;
    float z_loss = zmean * zmean;
    const float nn = (float)(NS * NE);
    float mean = esum / nn;
    float var = (esq - esum * esum / nn) / (nn - 1.0f);
    float load_loss = var / (mean * mean);
    out_aux[0] = 1e-3f * z_loss + 1e-3f * load_loss;
    int off = 0;
#pragma unroll
    for (int e = 0; e < NE; ++e) { offsets[e] = off; cursors[e] = off; off += counts[e]; }
    offsets[NE] = off;
  }
}

// ---------------- token lists ----------------
__global__ __launch_bounds__(256) void scatter_kernel(
    const int* __restrict__ expert_of, int* __restrict__ cursors,
    int* __restrict__ token_list)
{
  int n = blockIdx.x * 256 + threadIdx.x;
  int e = expert_of[n];
  int p = atomicAdd(&cursors[e], 1);
  token_list[p] = n;
}

// ---------------- grouped GEMM: weights-once, FIFO-clean pipeline ---------
template<int NSTEP, int LDA, int LDW, bool GATHER, bool ATOMIC>
__global__ __launch_bounds__(512, 4) void ggemm(
    const unsigned short* __restrict__ Ab,
    const float* __restrict__ Wa, const float* __restrict__ Wb,
    const int* __restrict__ offsets, const int* __restrict__ token_list,
    unsigned short* __restrict__ ga, unsigned short* __restrict__ gb,
    float* __restrict__ outp)
{
  const int e = blockIdx.z & 7;
  const int sel = blockIdx.z >> 3;          // matrix (GATHER) | k-half
  const int base = offsets[e], cnt = offsets[e + 1] - base;
  if (cnt <= 0) return;
  const int n0 = blockIdx.x * 32;
  int akoff;
  const float* W;
  unsigned short* g = nullptr;
  if constexpr (GATHER) {
    akoff = 0;
    W = (sel ? Wb : Wa) + (size_t)e * ((size_t)NH * ND) + (size_t)n0 * LDW;
    g = sel ? gb : ga;
  } else {
    akoff = sel * (NSTEP * 64);
    W = Wa + (size_t)e * ((size_t)NH * ND) + (size_t)n0 * LDW + akoff;
  }

  __shared__ __align__(16) unsigned short As[384 * 64];    // 48 KB single buf
  __shared__ __align__(16) unsigned short Bs[2][32 * 64];  //  8 KB dbuf
  __shared__ int rtk[384];

  const int t = threadIdx.x, l = t & 63, w = t >> 6;
  const int rl = l & 15, rq = l >> 4;
  const int wrow = w * 48;

  // B staging: thread t -> n-row t>>4 (0..31), f32 k-cols (t&15)*4..+3
  const int bn = t >> 4, bk4 = t & 15;
  const float* bp = W + (size_t)bn * LDW + bk4 * 4;
  const int bwoff = bn * 128 + ((((bk4 >> 1) ^ (bn & 7)) << 4)) + ((bk4 & 1) << 3);

  for (int c0 = 0; c0 < cnt; c0 += 384) {
    __syncthreads();
    for (int r = t; r < 384; r += 512) {
      int mc = c0 + r; if (mc > cnt - 1) mc = cnt - 1;
      rtk[r] = token_list[base + mc];
    }
    __syncthreads();

    // A-DMA sources: wave w stages its own 48 rows (6 instrs x 8 rows x 128B);
    // source 16B-block pre-swizzled by ^(row&7) = ^((l>>3)&7).
    const unsigned short* aSrc[6];
    {
      int r8 = l >> 3;
      int sblk = (l & 7) ^ (r8 & 7);
#pragma unroll
      for (int i = 0; i < 6; ++i) {
        int row = wrow + i * 8 + r8;
        size_t arow;
        if constexpr (GATHER) {
          arow = (size_t)rtk[row];
        } else {
          int mc = c0 + row; if (mc > cnt - 1) mc = cnt - 1;
          arow = (size_t)(base + mc);
        }
        aSrc[i] = Ab + arow * LDA + akoff + sblk * 8;
      }
    }
    char* aDst = (char*)As + w * 6144;
    auto stageA = [&](int k) {
#pragma unroll
      for (int i = 0; i < 6; ++i)
        gl_lds16(aSrc[i] + k * 64, aDst + i * 1024);
    };

    f32x4 bset[3];
    auto loadB = [&](int s, int k) {
      bset[s] = *(const f32x4*)(bp + (size_t)k * 64);
    };
    auto writeB = [&](int buf, int s) {
      *(u16x4*)((char*)&Bs[buf][0] + bwoff) = cvt4(bset[s]);
    };

    f32x4 acc[3][2] = {};
    bf16x8 af[3][2], bf[2][2];

    auto readFrags = [&](int buf) {
#pragma unroll
      for (int kk = 0; kk < 2; ++kk) {
#pragma unroll
        for (int i = 0; i < 3; ++i) {
          int row = wrow + i * 16 + rl;
          af[i][kk] = *(const bf16x8*)((const char*)As + row * 128 +
                        (((kk * 4 + rq) ^ (rl & 7)) << 4));
        }
#pragma unroll
        for (int j = 0; j < 2; ++j) {
          int row = j * 16 + rl;
          bf[j][kk] = *(const bf16x8*)((const char*)&Bs[buf][0] + row * 128 +
                        (((kk * 4 + rq) ^ (rl & 7)) << 4));
        }
      }
    };
    auto domfma = [&]() {
#pragma unroll
      for (int kk = 0; kk < 2; ++kk)
#pragma unroll
        for (int i = 0; i < 3; ++i)
#pragma unroll
          for (int j = 0; j < 2; ++j)
            acc[i][j] = __builtin_amdgcn_mfma_f32_16x16x32_bf16(
                af[i][kk], bf[j][kk], acc[i][j], 0, 0, 0);
    };

    // prologue: A(0) DMA, B sets for steps 0,1,2; publish B(0) into buf0.
    stageA(0);
    loadB(0, 0); loadB(1, 1); loadB(2, 2);
    writeB(0, 0);       // implicit vmcnt wait retires A(0)+B(0); keeps B(1),B(2)
    LBAR();

#pragma unroll
    for (int j = 0; j < NSTEP; ++j) {
      readFrags(j & 1);            // all frags -> regs (compiler-counted lgkm)
      if (j + 1 < NSTEP) {
        LBAR();                    // every wave done reading As/Bs
        SBAR();
        stageA(j + 1);             // 6 gl_lds (overwrite As)
        SBAR();
        writeB((j + 1) & 1, (j + 1) % 3);  // set loaded 2 steps ago
        if (j + 3 < NSTEP) {
          loadB(j % 3, j + 3);     // newest vmem op
          SBAR();
          domfma();                // reg-only, overlaps loads
          CBAR(1);                 // keep ONLY the just-issued B-load
        } else {
          SBAR();
          domfma();
          CBAR(0);                 // tail drain
        }
      } else {
        domfma();
      }
    }

    // epilogue
#pragma unroll
    for (int i = 0; i < 3; ++i) {
#pragma unroll
      for (int r = 0; r < 4; ++r) {
        int mrow = wrow + i * 16 + rq * 4 + r;
        int m = c0 + mrow;
        if (m < cnt) {
#pragma unroll
          for (int j = 0; j < 2; ++j) {
            int col = n0 + j * 16 + rl;
            float v = acc[i][j][r];
            if constexpr (ATOMIC) {
              atomicAdd(&outp[(size_t)rtk[mrow] * ND + col], v);
            } else {
              g[(size_t)(base + m) * NH + col] = f2b(v);
            }
          }
        }
      }
    }
  }
}

// ---------------- SwiGLU in-place: g1 <- silu(g1)*g2 ----------------
__global__ __launch_bounds__(256) void swiglu_kernel(
    unsigned short* __restrict__ g1, const unsigned short* __restrict__ g2)
{
  size_t i = ((size_t)blockIdx.x * 256 + threadIdx.x) * 8;
  u16x8 a = *(const u16x8*)(g1 + i);
  u16x8 b = *(const u16x8*)(g2 + i);
  u16x8 o;
#pragma unroll
  for (int j = 0; j < 8; ++j) {
    float av = __builtin_bit_cast(float, (unsigned int)a[j] << 16);
    float bv = __builtin_bit_cast(float, (unsigned int)b[j] << 16);
    o[j] = f2b(av / (1.f + expf(-av)) * bv);
  }
  *(u16x8*)(g1 + i) = o;
}

extern "C" void kernel_launch(void* const* d_in, const int* in_sizes, int n_in,
                              void* d_out, int out_size, void* d_ws, size_t ws_size,
                              hipStream_t stream)
{
  (void)in_sizes; (void)n_in; (void)out_size; (void)ws_size;
  const float* x  = (const float*)d_in[0];
  const float* Wr = (const float*)d_in[1];
  const float* W1 = (const float*)d_in[2];
  const float* W2 = (const float*)d_in[3];
  const float* W3 = (const float*)d_in[4];
  float* out = (float*)d_out;

  char* w = (char*)d_ws;
  float* probs    = (float*)(w + 0);        // 65536 B
  float* lse      = (float*)(w + 65536);    // 8192 B
  int* counts     = (int*)(w + 73728);      // 32 B
  int* cursors    = (int*)(w + 73760);      // 32 B
  int* offsets    = (int*)(w + 73792);      // 64 B
  int* expert_of  = (int*)(w + 73856);      // 8192 B
  int* token_list = (int*)(w + 82048);      // 8192 B
  unsigned short* g1 = (unsigned short*)(w + 131072);            // 14680064 B (-> h)
  unsigned short* g2 = g1 + (size_t)NTOK * NH;                   // 14680064 B
  unsigned short* xb = (unsigned short*)((char*)g2 + (size_t)NTOK * NH * 2); // 4 MB

  hipMemsetAsync(counts, 0, 32, stream);
  hipMemsetAsync(out, 0, (size_t)NTOK * ND * sizeof(float), stream);
  router_kernel<<<NTOK, 256, 0, stream>>>(x, Wr, probs, lse, counts, expert_of, xb);
  aux_offsets_kernel<<<1, 256, 0, stream>>>(probs, lse, counts, offsets, cursors,
                                            out + (size_t)NTOK * ND);
  scatter_kernel<<<NTOK / 256, 256, 0, stream>>>(expert_of, cursors, token_list);
  // g1 = x@W1^T, g2 = x@W2^T : weights once (z = expert(8) x matrix(2))
  ggemm<ND / 64, ND, ND, true, false><<<dim3(NH / 32, 1, 16), 512, 0, stream>>>(
      xb, W1, W2, offsets, token_list, g1, g2, nullptr);
  swiglu_kernel<<<(NTOK * NH) / (256 * 8), 256, 0, stream>>>(g1, g2);
  // out += h@W3^T : split-K=2 (z = expert(8) x khalf(2)), W3 once
  ggemm<(NH / 2) / 64, NH, NH, false, true><<<dim3(ND / 32, 1, 16), 512, 0, stream>>>(
      g1, W3, nullptr, offsets, token_list, nullptr, nullptr, out);
}

// Round 13
// 230.460 us; speedup vs baseline: 1.3998x; 1.0440x over previous
//
#include <hip/hip_runtime.h>
#include <hip/hip_bf16.h>
#include <math.h>

// MoE: B=2,S=1024,D=1024,E=8,H=3584, top-1 routing.
// router(+x->bf16) -> aux -> scatter
//  -> ggemm<GATHER>: g1=x@W1^T, g2=x@W2^T (z = expert x matrix)
//  -> swiglu (g1 <- silu(g1)*g2)
//  -> ggemm<ATOMIC>: out += h@W3^T (split-K=4, atomicAdd f32)
// r13: BIG TILE, max work per barrier. BM=256, BN=128, BK=64, 512thr/8waves
// (4M x 2N, per-wave 64x64 out, 32 MFMA/step/wave = 256 MFMA/block/step).
// A: gl_lds (pre-swizzled src, linear LDS); B: f32->2 named reg sets,
// write-late; ONE barrier/K-step, FIFO-clean: writeB's implicit vmcnt(4)
// retires only the 1-step-old B-set; CBAR(4) retires gl_lds, keeps newest
// B-loads in flight. LDS 97KB -> 1 block/CU (m201-style intra-block overlap).

#define NS 1024
#define ND 1024
#define NE 8
#define NH 3584
#define NTOK 2048

typedef float f32x4 __attribute__((ext_vector_type(4)));
typedef __bf16 bf16x8 __attribute__((ext_vector_type(8)));
typedef unsigned short u16x4 __attribute__((ext_vector_type(4)));
typedef unsigned short u16x8 __attribute__((ext_vector_type(8)));

#define CBAR(N) asm volatile("s_waitcnt vmcnt(" #N ") lgkmcnt(0)\n\ts_barrier" ::: "memory")
#define SBAR()  __builtin_amdgcn_sched_barrier(0)

__device__ __forceinline__ unsigned short f2b(float f) {
  return __builtin_bit_cast(unsigned short, (__bf16)f);
}
__device__ __forceinline__ u16x4 cvt4(f32x4 v) {
  u16x4 r;
  r[0] = f2b(v[0]); r[1] = f2b(v[1]); r[2] = f2b(v[2]); r[3] = f2b(v[3]);
  return r;
}
__device__ __forceinline__ void gl_lds16(const void* g, void* l) {
  __builtin_amdgcn_global_load_lds(
      (const __attribute__((address_space(1))) unsigned int*)g,
      (__attribute__((address_space(3))) unsigned int*)l, 16, 0, 0);
}

// ---------------- router (+ x f32 -> bf16) ----------------
__global__ __launch_bounds__(256) void router_kernel(
    const float* __restrict__ x, const float* __restrict__ Wr,
    float* __restrict__ probs, float* __restrict__ lse,
    int* __restrict__ counts, int* __restrict__ expert_of,
    unsigned short* __restrict__ xb)
{
  int n = blockIdx.x;
  int t = threadIdx.x;
  const float* xr = x + (size_t)n * ND;
  float xv[4];
#pragma unroll
  for (int j = 0; j < 4; ++j) xv[j] = xr[t + j * 256];
#pragma unroll
  for (int j = 0; j < 4; ++j)
    xb[(size_t)n * ND + t + j * 256] = f2b(xv[j]);
  float p[NE];
#pragma unroll
  for (int e = 0; e < NE; ++e) p[e] = 0.f;
#pragma unroll
  for (int j = 0; j < 4; ++j) {
    int d = t + j * 256;
#pragma unroll
    for (int e = 0; e < NE; ++e) p[e] += xv[j] * Wr[e * ND + d];
  }
#pragma unroll
  for (int e = 0; e < NE; ++e) {
#pragma unroll
    for (int o = 32; o > 0; o >>= 1) p[e] += __shfl_down(p[e], o, 64);
  }
  __shared__ float red[4][NE];
  int wid = t >> 6, lane = t & 63;
  if (lane == 0) {
#pragma unroll
    for (int e = 0; e < NE; ++e) red[wid][e] = p[e];
  }
  __syncthreads();
  if (t == 0) {
    float lg[NE];
#pragma unroll
    for (int e = 0; e < NE; ++e) lg[e] = red[0][e] + red[1][e] + red[2][e] + red[3][e];
    float m = lg[0]; int arg = 0;
#pragma unroll
    for (int e = 1; e < NE; ++e) if (lg[e] > m) { m = lg[e]; arg = e; }
    float s = 0.f, ex[NE];
#pragma unroll
    for (int e = 0; e < NE; ++e) { ex[e] = expf(lg[e] - m); s += ex[e]; }
    float inv = 1.f / s;
#pragma unroll
    for (int e = 0; e < NE; ++e) probs[n * NE + e] = ex[e] * inv;
    lse[n] = m + logf(s);
    expert_of[n] = arg;
    atomicAdd(&counts[arg], 1);
  }
}

// ---------------- aux losses + offsets ----------------
__global__ __launch_bounds__(256) void aux_offsets_kernel(
    const float* __restrict__ probs, const float* __restrict__ lse,
    const int* __restrict__ counts, int* __restrict__ offsets,
    int* __restrict__ cursors, float* __restrict__ out_aux)
{
  int t = threadIdx.x;
  float lsum = 0.f;
  for (int n = t; n < NTOK; n += 256) lsum += lse[n];
  float esum = 0.f, esq = 0.f;
  for (int i = t; i < NS * NE; i += 256) {
    float v = probs[i] + probs[NS * NE + i];
    esum += v; esq += v * v;
  }
  __shared__ float rb[3][4];
  int wid = t >> 6, lane = t & 63;
#pragma unroll
  for (int o = 32; o > 0; o >>= 1) {
    lsum += __shfl_down(lsum, o, 64);
    esum += __shfl_down(esum, o, 64);
    esq  += __shfl_down(esq, o, 64);
  }
  if (lane == 0) { rb[0][wid] = lsum; rb[1][wid] = esum; rb[2][wid] = esq; }
  __syncthreads();
  if (t == 0) {
    lsum = rb[0][0] + rb[0][1] + rb[0][2] + rb[0][3];
    esum = rb[1][0] + rb[1][1] + rb[1][2] + rb[1][3];
    esq  = rb[2][0] + rb[2][1] + rb[2][2] + rb[2][3];
    float zmean = lsum / (float)NTOK;
    float z_loss = zmean * zmean;
    const float nn = (float)(NS * NE);
    float mean = esum / nn;
    float var = (esq - esum * esum / nn) / (nn - 1.0f);
    float load_loss = var / (mean * mean);
    out_aux[0] = 1e-3f * z_loss + 1e-3f * load_loss;
    int off = 0;
#pragma unroll
    for (int e = 0; e < NE; ++e) { offsets[e] = off; cursors[e] = off; off += counts[e]; }
    offsets[NE] = off;
  }
}

// ---------------- token lists ----------------
__global__ __launch_bounds__(256) void scatter_kernel(
    const int* __restrict__ expert_of, int* __restrict__ cursors,
    int* __restrict__ token_list)
{
  int n = blockIdx.x * 256 + threadIdx.x;
  int e = expert_of[n];
  int p = atomicAdd(&cursors[e], 1);
  token_list[p] = n;
}

// ---------------- grouped GEMM: big tile, one barrier per K-step ----------
template<int NSTEP, int LDA, int LDW, bool GATHER, bool ATOMIC>
__global__ __launch_bounds__(512, 1) void ggemm(
    const unsigned short* __restrict__ Ab,
    const float* __restrict__ Wa, const float* __restrict__ Wb,
    const int* __restrict__ offsets, const int* __restrict__ token_list,
    unsigned short* __restrict__ ga, unsigned short* __restrict__ gb,
    float* __restrict__ outp)
{
  const int e = blockIdx.z & 7;
  const int sel = blockIdx.z >> 3;          // matrix (GATHER) | k-slice
  const int base = offsets[e], cnt = offsets[e + 1] - base;
  const int m0 = blockIdx.y * 256;
  if (m0 >= cnt) return;
  const int n0 = blockIdx.x * 128;
  const float* W;
  unsigned short* g = nullptr;
  int akoff = 0;
  if constexpr (GATHER) {
    W = (sel ? Wb : Wa) + (size_t)e * ((size_t)NH * ND) + (size_t)n0 * LDW;
    g = sel ? gb : ga;
  } else {
    akoff = sel * (NSTEP * 64);
    W = Wa + (size_t)e * ((size_t)NH * ND) + (size_t)n0 * LDW + akoff;
  }

  __shared__ __align__(16) unsigned short As[2][256 * 64];    // 2 x 32 KB
  __shared__ __align__(16) unsigned short Bsh[2][128 * 64];   // 2 x 16 KB
  __shared__ int rtk[256];

  const int t = threadIdx.x, l = t & 63, w = t >> 6;
  const int rl = l & 15, rq = l >> 4;
  const int wm = (w >> 1) * 64, wn = (w & 1) * 64;

  if (t < 256) {
    int mc = m0 + t; if (mc > cnt - 1) mc = cnt - 1;
    rtk[t] = token_list[base + mc];
  }
  __syncthreads();

  // A gl_lds: wave w stages rows w*32..+31 (4 instr x 8 rows x 128B);
  // source 16B-block pre-swizzled by ^(row&7) so frag reads can XOR same way.
  const unsigned short* aSrc[4];
  {
    int r8 = l >> 3;
    int sb = (l & 7) ^ (r8 & 7);
#pragma unroll
    for (int i = 0; i < 4; ++i) {
      int row = w * 32 + i * 8 + r8;
      size_t arow;
      if constexpr (GATHER) {
        arow = (size_t)rtk[row];
      } else {
        int mc = m0 + row; if (mc > cnt - 1) mc = cnt - 1;
        arow = (size_t)(base + mc);
      }
      aSrc[i] = Ab + arow * LDA + akoff + sb * 8;
    }
  }
  auto stageA = [&](int buf, int k) {
    char* d = (char*)&As[buf][0] + w * 4096;
#pragma unroll
    for (int i = 0; i < 4; ++i)
      gl_lds16(aSrc[i] + (size_t)k * 64, d + i * 1024);
  };

  // B staging: 4 rows/thread (row = w*16 + i*4 + (l>>4)), 16 f32/row chunk,
  // 256B contiguous per 16 lanes; swizzled bf16 LDS writes (8B each).
  const float* bp[4];
  int bwo[4];
  {
    int c16 = l & 15;
#pragma unroll
    for (int i = 0; i < 4; ++i) {
      int row = w * 16 + i * 4 + (l >> 4);
      bp[i] = W + (size_t)row * LDW + c16 * 4;
      bwo[i] = row * 128 + (((c16 >> 1) ^ (row & 7)) << 4) + ((c16 & 1) << 3);
    }
  }
  f32x4 sA[4], sB[4];
  auto loadB = [&](f32x4 (&s)[4], int k) {
#pragma unroll
    for (int i = 0; i < 4; ++i) s[i] = *(const f32x4*)(bp[i] + (size_t)k * 64);
  };
  auto writeB = [&](int buf, const f32x4 (&s)[4]) {
#pragma unroll
    for (int i = 0; i < 4; ++i)
      *(u16x4*)((char*)&Bsh[buf][0] + bwo[i]) = cvt4(s[i]);
  };

  f32x4 acc[4][4] = {};
  bf16x8 af[4][2], bf[4][2];
  auto frags = [&](int buf) {
#pragma unroll
    for (int kk = 0; kk < 2; ++kk) {
      const int gx = ((kk * 4 + rq) ^ (rl & 7)) << 4;
#pragma unroll
      for (int i = 0; i < 4; ++i)
        af[i][kk] = *(const bf16x8*)((const char*)&As[buf][0] + (wm + i * 16 + rl) * 128 + gx);
#pragma unroll
      for (int j = 0; j < 4; ++j)
        bf[j][kk] = *(const bf16x8*)((const char*)&Bsh[buf][0] + (wn + j * 16 + rl) * 128 + gx);
    }
  };
  auto domfma = [&]() {
    __builtin_amdgcn_s_setprio(1);
#pragma unroll
    for (int kk = 0; kk < 2; ++kk)
#pragma unroll
      for (int i = 0; i < 4; ++i)
#pragma unroll
        for (int j = 0; j < 4; ++j)
          acc[i][j] = __builtin_amdgcn_mfma_f32_16x16x32_bf16(
              af[i][kk], bf[j][kk], acc[i][j], 0, 0, 0);
    __builtin_amdgcn_s_setprio(0);
  };

  // prologue: A(0) DMA; B(0) -> buf0 (full drain, once); B(1) in flight.
  stageA(0, 0); SBAR();
  loadB(sA, 0); SBAR();
  writeB(0, sA); SBAR();
  loadB(sB, 1); SBAR();
  CBAR(4);                 // keep sB's 4 loads in flight

  for (int k = 0; k + 2 < NSTEP; k += 2) {
    // even step k (reads buf0)
    stageA(1, k + 1); SBAR();
    frags(0);
    domfma();
    writeB(1, sB); SBAR();          // implicit vmcnt(4): retire sB, keep gl_lds
    loadB(sA, k + 2); SBAR();
    CBAR(4);                        // retire gl_lds(k+1); keep sA loads
    // odd step k+1 (reads buf1)
    stageA(0, k + 2); SBAR();
    frags(1);
    domfma();
    writeB(0, sA); SBAR();
    if (k + 3 < NSTEP) {
      loadB(sB, k + 3); SBAR();
      CBAR(4);
    } else {
      CBAR(0);
    }
  }
  // tail: step NSTEP-2 (buf0), NSTEP-1 (buf1)
  stageA(1, NSTEP - 1); SBAR();
  frags(0);
  domfma();
  writeB(1, sB); SBAR();
  CBAR(0);
  frags(1);
  domfma();

  // epilogue
#pragma unroll
  for (int i = 0; i < 4; ++i)
#pragma unroll
    for (int r = 0; r < 4; ++r) {
      int mrel = wm + i * 16 + rq * 4 + r;
      int m = m0 + mrel;
      if (m < cnt) {
#pragma unroll
        for (int j = 0; j < 4; ++j) {
          int col = n0 + wn + j * 16 + rl;
          float v = acc[i][j][r];
          if constexpr (ATOMIC) {
            atomicAdd(&outp[(size_t)rtk[mrel] * ND + col], v);
          } else {
            g[(size_t)(base + m) * NH + col] = f2b(v);
          }
        }
      }
    }
}

// ---------------- SwiGLU in-place: g1 <- silu(g1)*g2 ----------------
__global__ __launch_bounds__(256) void swiglu_kernel(
    unsigned short* __restrict__ g1, const unsigned short* __restrict__ g2)
{
  size_t i = ((size_t)blockIdx.x * 256 + threadIdx.x) * 8;
  u16x8 a = *(const u16x8*)(g1 + i);
  u16x8 b = *(const u16x8*)(g2 + i);
  u16x8 o;
#pragma unroll
  for (int j = 0; j < 8; ++j) {
    float av = __builtin_bit_cast(float, (unsigned int)a[j] << 16);
    float bv = __builtin_bit_cast(float, (unsigned int)b[j] << 16);
    o[j] = f2b(av / (1.f + expf(-av)) * bv);
  }
  *(u16x8*)(g1 + i) = o;
}

extern "C" void kernel_launch(void* const* d_in, const int* in_sizes, int n_in,
                              void* d_out, int out_size, void* d_ws, size_t ws_size,
                              hipStream_t stream)
{
  (void)in_sizes; (void)n_in; (void)out_size; (void)ws_size;
  const float* x  = (const float*)d_in[0];
  const float* Wr = (const float*)d_in[1];
  const float* W1 = (const float*)d_in[2];
  const float* W2 = (const float*)d_in[3];
  const float* W3 = (const float*)d_in[4];
  float* out = (float*)d_out;

  char* w = (char*)d_ws;
  float* probs    = (float*)(w + 0);        // 65536 B
  float* lse      = (float*)(w + 65536);    // 8192 B
  int* counts     = (int*)(w + 73728);      // 32 B
  int* cursors    = (int*)(w + 73760);      // 32 B
  int* offsets    = (int*)(w + 73792);      // 64 B
  int* expert_of  = (int*)(w + 73856);      // 8192 B
  int* token_list = (int*)(w + 82048);      // 8192 B
  unsigned short* g1 = (unsigned short*)(w + 131072);            // 14680064 B (-> h)
  unsigned short* g2 = g1 + (size_t)NTOK * NH;                   // 14680064 B
  unsigned short* xb = (unsigned short*)((char*)g2 + (size_t)NTOK * NH * 2); // 4 MB

  hipMemsetAsync(counts, 0, 32, stream);
  hipMemsetAsync(out, 0, (size_t)NTOK * ND * sizeof(float), stream);
  router_kernel<<<NTOK, 256, 0, stream>>>(x, Wr, probs, lse, counts, expert_of, xb);
  aux_offsets_kernel<<<1, 256, 0, stream>>>(probs, lse, counts, offsets, cursors,
                                            out + (size_t)NTOK * ND);
  scatter_kernel<<<NTOK / 256, 256, 0, stream>>>(expert_of, cursors, token_list);
  // g1 = x@W1^T, g2 = x@W2^T  (z = expert(8) x matrix(2); y = 2 M-tiles)
  ggemm<ND / 64, ND, ND, true, false><<<dim3(NH / 128, 2, 16), 512, 0, stream>>>(
      xb, W1, W2, offsets, token_list, g1, g2, nullptr);
  swiglu_kernel<<<(NTOK * NH) / (256 * 8), 256, 0, stream>>>(g1, g2);
  // out += h@W3^T  (z = expert(8) x kslice(4); split-K=4 atomicAdd)
  ggemm<(NH / 4) / 64, NH, NH, false, true><<<dim3(ND / 128, 2, 32), 512, 0, stream>>>(
      g1, W3, nullptr, offsets, token_list, nullptr, nullptr, out);
}